// Round 11
// baseline (511.979 us; speedup 1.0000x reference)
//
#include <hip/hip_runtime.h>
#include <stdint.h>

#define TOKENS 8192
#define KIN    4096
#define NOUT   11008

// ---- 128x128 GEMM geometry (i8, BK=128 => 128 B/row) ----
#define BM 128
#define BN 128
#define BK 128
#define NT    (KIN / BK)      // 32 K-tiles
#define NTROW (TOKENS / BM)   // 64
#define NTCOL (NOUT / BN)     // 86
#define NWG   (NTROW * NTCOL) // 5504 = 8 XCDs x 688

using i32x4 = __attribute__((ext_vector_type(4))) int;

static __device__ __forceinline__ void gload_lds16(const void* g, void* l) {
  __builtin_amdgcn_global_load_lds((const __attribute__((address_space(1))) void*)g,
                                   (__attribute__((address_space(3))) void*)l,
                                   16, 0, 0);
}

static __device__ __forceinline__ int clamp_q(float f) {
  int q = (int)rintf(f);
  q = q > 127 ? 127 : q;
  q = q < -127 ? -127 : q;
  return q;
}

static __device__ __forceinline__ int pack4(int a, int b, int c, int d) {
  return (a & 0xff) | ((b & 0xff) << 8) | ((c & 0xff) << 16) | ((d & 0xff) << 24);
}

// ---- kernel 1: fused quantization ----
// bid < NOUT:  weight row c -> i8, written in MFMA-FRAGMENT-PACKED layout:
//   Bp[cb][t][kk][lane][16B], cb=c>>4, lane=hi*16+(c&15), k=t*128+kk*64+hi*16+kb
//   => each GEMM B-fragment load is one coalesced 1KB wave-load (no LDS for B).
// bid >= NOUT: input row -> i8 row-major (LDS staging path needs rows).
__global__ __launch_bounds__(256) void quant_fused_k(const float* __restrict__ W,
                                                     const float* __restrict__ X,
                                                     signed char* __restrict__ Bp,
                                                     signed char* __restrict__ Xq,
                                                     float* __restrict__ scale_w,
                                                     float* __restrict__ scale_x) {
  const int bid = blockIdx.x;
  const int th  = threadIdx.x;
  if (bid < NOUT) {
    const int c = bid;                               // output col = W row
    const float4* wr = reinterpret_cast<const float4*>(W + (size_t)c * KIN);
    float4 v[4];
    double s = 0.0;
#pragma unroll
    for (int i = 0; i < 4; ++i) {
      v[i] = wr[th + i * 256];
      s += fabs((double)v[i].x) + fabs((double)v[i].y) +
           fabs((double)v[i].z) + fabs((double)v[i].w);
    }
#pragma unroll
    for (int off = 32; off > 0; off >>= 1) s += __shfl_down(s, off);
    __shared__ double redd[4];
    if ((th & 63) == 0) redd[th >> 6] = s;
    __syncthreads();
    const float sc = (float)((redd[0] + redd[1] + redd[2] + redd[3]) * (1.0 / KIN));
    if (th == 0) scale_w[c] = sc;
    const int cb = c >> 4, ci = c & 15;
    int* qp = reinterpret_cast<int*>(Bp + (size_t)cb * 65536);
#pragma unroll
    for (int i = 0; i < 4; ++i) {
      const int w  = th + i * 256;                   // int32 word idx, k bytes 4w..4w+3
      const int t  = w >> 5;
      const int kk = (w >> 4) & 1;
      const int hi = (w >> 2) & 3;
      const int kb = w & 3;
      qp[t * 512 + kk * 256 + (hi * 16 + ci) * 4 + kb] =
          pack4(clamp_q(v[i].x / sc), clamp_q(v[i].y / sc),
                clamp_q(v[i].z / sc), clamp_q(v[i].w / sc));
    }
  } else {
    const int row = bid - NOUT;
    const float4* xr = reinterpret_cast<const float4*>(X + (size_t)row * KIN);
    float4 v[4];
    float amax = 0.f;
#pragma unroll
    for (int i = 0; i < 4; ++i) {
      v[i] = xr[th + i * 256];
      amax = fmaxf(amax, fmaxf(fmaxf(fabsf(v[i].x), fabsf(v[i].y)),
                               fmaxf(fabsf(v[i].z), fabsf(v[i].w))));
    }
#pragma unroll
    for (int off = 32; off > 0; off >>= 1) amax = fmaxf(amax, __shfl_down(amax, off));
    __shared__ float redf[4];
    if ((th & 63) == 0) redf[th >> 6] = amax;
    __syncthreads();
    amax = fmaxf(fmaxf(redf[0], redf[1]), fmaxf(redf[2], redf[3]));
    amax = fmaxf(amax, 1e-30f);
    const float inv = 127.0f / amax;
    if (th == 0) scale_x[row] = amax * (1.0f / 127.0f);
    int* qr = reinterpret_cast<int*>(Xq + (size_t)row * KIN);
#pragma unroll
    for (int i = 0; i < 4; ++i)
      qr[th + i * 256] = pack4(clamp_q(v[i].x * inv), clamp_q(v[i].y * inv),
                               clamp_q(v[i].z * inv), clamp_q(v[i].w * inv));
  }
}

// ---- kernel 2: 128x128x128 i8 GEMM; A via LDS, B direct global->VGPR ----
// out[t,o] = s_x[t]*s_w[o]*(Xq.Wq)_i32 + bias[o].
//
// R11 (AITER flatmm pattern): diagnosis — per-CU LDS pipe (~196KB reads +
// 64KB writes per tile) serializes with the MFMA pipe; R10 proved the stall
// is a shared-CU resource (2 blocks/CU didn't move it). Fix: B fragments come
// from the packed layout via coalesced global_load_dwordx4 directly into
// VGPRs (double-buffered bP/bQ, loaded 1 tile ahead -> VMEM overlaps MFMA;
// no LDS writes/reads/swizzle for B). A keeps the proven LDS path (2-way
// reuse). LDS traffic halves; L2 demand ~96KB/tile/CU ~ 22.7 TB/s < ceiling.
//
// Per tile t (cur = (t&1)*16384):
//   STAGE_A(t+1) -> cur^16384   (overwrites t-1, consumed last tile)
//   LOAD_B(t+1)  -> alternate reg set (8 coalesced dwordx4)
//   ds_read A(t) frags (8 b128) ; MFMA x32 with current B regs
//   vmcnt(0)  (stage+B issued ~2000cy earlier, L2-hit ~ free) ; s_barrier
__global__ __launch_bounds__(256, 2) void gemm_k(const signed char* __restrict__ Xq,
                                                 const signed char* __restrict__ Bp,
                                                 const float* __restrict__ scale_x,
                                                 const float* __restrict__ scale_w,
                                                 const float* __restrict__ bias,
                                                 float* __restrict__ out) {
  __shared__ alignas(16) char lds[32768];   // A only: [buf][128 rows][128B]

  // ---- supertile swizzle: 5504 = 8 XCDs x 688; 8-trow band per XCD,
  // 8x4 chunks (21 full = 672) + 8x2 tail ----
  const int xcd = (int)blockIdx.x & 7;
  const int seq = (int)blockIdx.x >> 3;          // 0..687
  int trow, tcol;
  if (seq < 672) {
    const int chunk = seq >> 5;                  // 0..20
    const int rem   = seq & 31;
    trow = xcd * 8 + (rem >> 2);
    tcol = chunk * 4 + (rem & 3);
  } else {
    const int rem = seq - 672;                   // 0..15
    trow = xcd * 8 + (rem >> 1);
    tcol = 84 + (rem & 1);
  }

  const int tid  = (int)threadIdx.x;
  const int lane = tid & 63;
  const int wave = tid >> 6;   // 0..3
  const int wm   = wave >> 1;  // 0..1 : M half (64 rows)
  const int wn   = wave & 1;   // 0..1 : N half (64 cols)

  // ---- A staging (inverse-swizzled global source, linear LDS dest) ----
  const int l8 = lane >> 3;                          // row within 8-row group
  const size_t rowb = (size_t)KIN;                   // 4096 B per row (i8)
  const int swzl = ((lane & 7) ^ l8) * 16;           // pre-swizzled slot
  const char* gA = (const char*)Xq + (size_t)(trow * BM + wave * 32 + l8) * rowb + swzl;
  char* lA = lds + wave * 4096;                      // + buf*16384 ; + g*1024

#define STAGE_A(BUF, KS) do {                                                \
    _Pragma("unroll") for (int g = 0; g < 4; ++g)                            \
      gload_lds16(gA + (size_t)(g * 8) * rowb + (KS), lA + (BUF) + g * 1024);\
  } while (0)

  // ---- B direct-load base: packed Bp[cb][t][kk][lane][16] ----
  const char* gBf = (const char*)Bp + (size_t)(tcol * 8 + wn * 4) * 65536 + lane * 16;

  // ---- A ds_read bases (swizzled) ----
  const int lr = lane & 15;
  const int hi = lane >> 4;
  const int swz0 = (hi * 16) ^ ((lr & 7) << 4);
  const int swz[2] = { swz0, swz0 ^ 64 };
  const char* rdA = lds + wm * 8192 + lr * 128;      // A[buf][wm*64+mf*16+lr][.]

  i32x4 acc[4][4];
#pragma unroll
  for (int m = 0; m < 4; ++m)
#pragma unroll
    for (int n = 0; n < 4; ++n) acc[m][n] = (i32x4){0, 0, 0, 0};
  i32x4 afr[4][2];
  i32x4 bP[4][2], bQ[4][2];   // B double-buffer, static names (rule #20)

#define SB() __builtin_amdgcn_sched_barrier(0)

#define LOAD_B(DST, T) do {                                                   \
    _Pragma("unroll") for (int nf = 0; nf < 4; ++nf)                          \
    _Pragma("unroll") for (int kk = 0; kk < 2; ++kk)                          \
      DST[nf][kk] = *(const i32x4*)(gBf + nf * 65536 + (T) * 2048 + kk * 1024);\
  } while (0)

#define TILE(T, CUR, BU, BNX) do {                                           \
    if ((T) + 1 < NT) {                                                      \
      STAGE_A((CUR) ^ 16384, (size_t)((T) + 1) * 128);                       \
      LOAD_B(BNX, (T) + 1);                                                  \
    }                                                                        \
    _Pragma("unroll") for (int mf = 0; mf < 4; ++mf) {                       \
      afr[mf][0] = *(const i32x4*)(rdA + (CUR) + mf * 2048 + swz[0]);        \
      afr[mf][1] = *(const i32x4*)(rdA + (CUR) + mf * 2048 + swz[1]);        \
    }                                                                        \
    __builtin_amdgcn_s_setprio(1);                                           \
    _Pragma("unroll") for (int mf = 0; mf < 4; ++mf)                         \
    _Pragma("unroll") for (int nf = 0; nf < 4; ++nf)                         \
    _Pragma("unroll") for (int kk = 0; kk < 2; ++kk)                         \
      acc[mf][nf] = __builtin_amdgcn_mfma_i32_16x16x64_i8(                   \
          afr[mf][kk], BU[nf][kk], acc[mf][nf], 0, 0, 0);                    \
    __builtin_amdgcn_s_setprio(0);                                           \
    SB();                                                                    \
    asm volatile("s_waitcnt vmcnt(0)" ::: "memory");                         \
    __builtin_amdgcn_s_barrier();                                            \
    SB();                                                                    \
  } while (0)

  // ---- prologue: stage A(0); load B(0)->bP; drain; sync ----
  STAGE_A(0, 0);
  LOAD_B(bP, 0);
  asm volatile("s_waitcnt vmcnt(0)" ::: "memory");
  __builtin_amdgcn_s_barrier();
  SB();

  for (int tt = 0; tt < NT; tt += 2) {
    TILE(tt,     0,     bP, bQ);
    TILE(tt + 1, 16384, bQ, bP);
  }

  // ---- epilogue: C/D layout col = lane&15, row = (lane>>4)*4 + reg ----
  const int gr_base = trow * BM + wm * 64 + hi * 4;
  const int gc_base = tcol * BN + wn * 64 + lr;
  float sx[4][4];
#pragma unroll
  for (int mf = 0; mf < 4; ++mf)
#pragma unroll
    for (int j = 0; j < 4; ++j) sx[mf][j] = scale_x[gr_base + mf * 16 + j];
#pragma unroll
  for (int nf = 0; nf < 4; ++nf) {
    const int gc = gc_base + nf * 16;
    const float sw = scale_w[gc];
    const float bb = bias[gc];
#pragma unroll
    for (int mf = 0; mf < 4; ++mf) {
      const size_t rb = (size_t)(gr_base + mf * 16) * NOUT + gc;
#pragma unroll
      for (int j = 0; j < 4; ++j)
        __builtin_nontemporal_store((float)acc[mf][nf][j] * (sx[mf][j] * sw) + bb,
                                    &out[rb + (size_t)j * NOUT]);
    }
  }
#undef STAGE_A
#undef LOAD_B
#undef TILE
#undef SB
}

extern "C" void kernel_launch(void* const* d_in, const int* in_sizes, int n_in,
                              void* d_out, int out_size, void* d_ws, size_t ws_size,
                              hipStream_t stream) {
  const float* X  = (const float*)d_in[0];   // [8192, 4096] fp32
  const float* W  = (const float*)d_in[1];   // [11008, 4096] fp32
  const float* Bi = (const float*)d_in[2];   // [11008] fp32
  float* out = (float*)d_out;                // [8192, 11008] fp32

  const size_t xq_bytes = (size_t)TOKENS * KIN;      // 32 MiB
  const size_t bp_bytes = (size_t)NOUT * KIN;        // 43 MiB (packed layout)
  const size_t need = xq_bytes + bp_bytes + (size_t)(NOUT + TOKENS) * sizeof(float);
  if (ws_size < need) return;  // needs ~76 MB scratch

  char* ws = (char*)d_ws;
  signed char* Xq = (signed char*)ws;
  signed char* Bp = (signed char*)(ws + xq_bytes);
  float* scale_w = (float*)(ws + xq_bytes + bp_bytes);
  float* scale_x = scale_w + NOUT;

  quant_fused_k<<<NOUT + TOKENS, 256, 0, stream>>>(W, X, Bp, Xq, scale_w, scale_x);
  gemm_k<<<NWG, 256, 0, stream>>>(Xq, Bp, scale_x, scale_w, Bi, out);
}

// Round 12
// 429.929 us; speedup vs baseline: 1.1908x; 1.1908x over previous
//
#include <hip/hip_runtime.h>
#include <stdint.h>

#define TOKENS 8192
#define KIN    4096
#define NOUT   11008

// ---- 256x256 GEMM geometry (i8, BK=128 => 128 B/row) ----
#define BM 256
#define BN 256
#define BK 128
#define NT    (KIN / BK)      // 32 K-tiles
#define NTROW (TOKENS / BM)   // 32
#define NTCOL (NOUT / BN)     // 43
#define NWG   (NTROW * NTCOL) // 1376 = 8 XCDs x 172

using i32x4 = __attribute__((ext_vector_type(4))) int;

static __device__ __forceinline__ void gload_lds16(const void* g, void* l) {
  __builtin_amdgcn_global_load_lds((const __attribute__((address_space(1))) void*)g,
                                   (__attribute__((address_space(3))) void*)l,
                                   16, 0, 0);
}

static __device__ __forceinline__ int clamp_q(float f) {
  int q = (int)rintf(f);
  q = q > 127 ? 127 : q;
  q = q < -127 ? -127 : q;
  return q;
}

static __device__ __forceinline__ int pack4(int a, int b, int c, int d) {
  return (a & 0xff) | ((b & 0xff) << 8) | ((c & 0xff) << 16) | ((d & 0xff) << 24);
}

// ---- kernel 1: fused quantization (weight rows, then input rows) ----
__global__ __launch_bounds__(256) void quant_fused_k(const float* __restrict__ W,
                                                     const float* __restrict__ X,
                                                     signed char* __restrict__ Wq,
                                                     signed char* __restrict__ Xq,
                                                     float* __restrict__ scale_w,
                                                     float* __restrict__ scale_x) {
  const int bid = blockIdx.x;
  const int t   = threadIdx.x;
  if (bid < NOUT) {
    const int row = bid;
    const float4* wr = reinterpret_cast<const float4*>(W + (size_t)row * KIN);
    float4 v[4];
    double s = 0.0;
#pragma unroll
    for (int i = 0; i < 4; ++i) {
      v[i] = wr[t + i * 256];
      s += fabs((double)v[i].x) + fabs((double)v[i].y) +
           fabs((double)v[i].z) + fabs((double)v[i].w);
    }
#pragma unroll
    for (int off = 32; off > 0; off >>= 1) s += __shfl_down(s, off);
    __shared__ double redd[4];
    if ((t & 63) == 0) redd[t >> 6] = s;
    __syncthreads();
    const float sc = (float)((redd[0] + redd[1] + redd[2] + redd[3]) * (1.0 / KIN));
    if (t == 0) scale_w[row] = sc;
    int* qr = reinterpret_cast<int*>(Wq + (size_t)row * KIN);
#pragma unroll
    for (int i = 0; i < 4; ++i)
      qr[t + i * 256] = pack4(clamp_q(v[i].x / sc), clamp_q(v[i].y / sc),
                              clamp_q(v[i].z / sc), clamp_q(v[i].w / sc));
  } else {
    const int row = bid - NOUT;
    const float4* xr = reinterpret_cast<const float4*>(X + (size_t)row * KIN);
    float4 v[4];
    float amax = 0.f;
#pragma unroll
    for (int i = 0; i < 4; ++i) {
      v[i] = xr[t + i * 256];
      amax = fmaxf(amax, fmaxf(fmaxf(fabsf(v[i].x), fabsf(v[i].y)),
                               fmaxf(fabsf(v[i].z), fabsf(v[i].w))));
    }
#pragma unroll
    for (int off = 32; off > 0; off >>= 1) amax = fmaxf(amax, __shfl_down(amax, off));
    __shared__ float redf[4];
    if ((t & 63) == 0) redf[t >> 6] = amax;
    __syncthreads();
    amax = fmaxf(fmaxf(redf[0], redf[1]), fmaxf(redf[2], redf[3]));
    amax = fmaxf(amax, 1e-30f);
    const float inv = 127.0f / amax;
    if (t == 0) scale_x[row] = amax * (1.0f / 127.0f);
    int* qr = reinterpret_cast<int*>(Xq + (size_t)row * KIN);
#pragma unroll
    for (int i = 0; i < 4; ++i)
      qr[t + i * 256] = pack4(clamp_q(v[i].x * inv), clamp_q(v[i].y * inv),
                              clamp_q(v[i].z * inv), clamp_q(v[i].w * inv));
  }
}

// ---- kernel 2: 256x256x128 i8 GEMM — faithful m201 8-phase fine interleave ----
// out[t,o] = s_x[t]*s_w[o]*(Xq.Wq)_i32 + bias[o].  Row-major [row][K] i8.
//
// R12: m196 lesson — the lever is the FINE ds_read || global_load_lds || MFMA
// interleave: 2 gloads per phase spread over all 8 phases (not bursts of 8),
// counted vmcnt(4) at only ph4/ph8 per 2-tile iteration. All prior i8 rounds
// ran the coarse variant (-7..-27% per m196).
//
// LDS: A[buf][256][128B] at buf*32768; B at 65536+buf*32768. b0=tile T (even),
// b1=tile T+1. Both-sides XOR swizzle as before.
//
// Per 2-tile iter (phases; each phase = reads|stage -> bar -> lgkm0 -> 16 MFMA -> bar):
//  ph1: rd A(T)m0-3(8)+B(T)n0-1(4); stage A(T+1)h0->b1; lgkm8   ; MFMA m0-3xn0-1
//  ph2: rd B(T)n2-3(4);             stage A(T+1)h1->b1          ; MFMA m0-3xn2-3
//  ph3: rd A(T)m4-7(8);             stage B(T+2)h0->b0          ; MFMA m4-7xn2-3
//  ph4:                             stage B(T+2)h1->b0          ; MFMA m4-7xn0-1; vmcnt(4)
//  ph5-8: same on tile T+1/b1, staging A(T+2)h0,h1->b0, B(T+3)h0,h1->b1; vmcnt(4) @ph8
//
// Hazard proof: stage-legality (after last read of overwritten data, enforced by
// phase-end barriers): A-b1 read ph5/ph7 prev iter < ph1; B-b0 read ph1-2 < ph3;
// A-b0 read ph1/ph3 < ph5; B-b1 read ph5-6 < ph7. Land-deadlines with vmcnt(4)
// (landed = staged >= 2 phases before the wait): A(T+1) ph1-2 -> @ph4, read ph5 ok;
// B(T+2) ph3-4 -> @ph8, read next ph1 ok; A(T+2) ph5-6 -> @ph8, read next ph1 ok;
// B(T+3) ph7-8 -> @next ph4, read next ph5 ok. Tail: vmcnt(0) when stages skipped.
__global__ __launch_bounds__(512, 2) void gemm_k(const signed char* __restrict__ Xq,
                                                 const signed char* __restrict__ Wq,
                                                 const float* __restrict__ scale_x,
                                                 const float* __restrict__ scale_w,
                                                 const float* __restrict__ bias,
                                                 float* __restrict__ out) {
  __shared__ alignas(16) char lds[131072];

  // ---- supertile swizzle (R6): 1376 = 8 XCDs x 172; 172 = 10 x (4x4) + 4x3 ----
  const int xcd = (int)blockIdx.x & 7;
  const int seq = (int)blockIdx.x >> 3;          // 0..171
  int trow, tcol;
  if (seq < 160) {
    const int chunk = seq >> 4;                  // 0..9
    const int rem   = seq & 15;
    trow = xcd * 4 + (rem >> 2);
    tcol = chunk * 4 + (rem & 3);
  } else {
    const int rem = seq - 160;                   // 0..11
    trow = xcd * 4 + rem / 3;
    tcol = 40 + rem % 3;
  }

  const int tid  = (int)threadIdx.x;
  const int lane = tid & 63;
  const int wave = tid >> 6;   // 0..7
  const int wm   = wave >> 2;  // 0..1 : M half (128 rows)
  const int wn   = wave & 3;   // 0..3 : N quarter (64 cols)

  // ---- staging lane addresses (inverse-swizzled global source, linear LDS dest) ----
  const int l8 = lane >> 3;
  const size_t rowb = (size_t)KIN;                   // 4096 B per row (i8)
  const int swzl = ((lane & 7) ^ l8) * 16;
  const char* gA = (const char*)Xq + (size_t)(trow * BM + wave * 16 + l8) * rowb + swzl;
  const char* gB = (const char*)Wq + (size_t)(tcol * BN + wave * 16 + l8) * rowb + swzl;
  char* lA = lds + wave * 2048;            // + buf*32768 + h*16384 (+1024 for 2nd gload)
  char* lB = lds + 65536 + wave * 2048;

  // one STAGE = 2 gloads = one half-tile (all 8 waves together)
#define STAGE(gp, lp, koff) do {                                             \
    gload_lds16((gp) + (koff), (lp));                                        \
    gload_lds16((gp) + (koff) + (size_t)(8 * 4096), (char*)(lp) + 1024);     \
  } while (0)

  // ---- ds_read bases (swizzled) ----
  const int lr = lane & 15;
  const int hi = lane >> 4;
  const int swz0 = (hi * 16) ^ ((lr & 7) << 4);
  const int swz[2] = { swz0, swz0 ^ 64 };
  const char* rdA = lds + wm * 16384 + lr * 128;
  const char* rdB = lds + 65536 + (wn >> 1) * 16384 + ((wn & 1) * 64 + lr) * 128;

  i32x4 acc[8][4];
#pragma unroll
  for (int m = 0; m < 8; ++m)
#pragma unroll
    for (int n = 0; n < 4; ++n) acc[m][n] = (i32x4){0, 0, 0, 0};
  i32x4 afr[4][2], bfr[4][2];   // afr reused m0-3 -> m4-7 (R4/R8 budget, no spill)

#define RD_A(mf, mb, BUF) do {                                                \
    afr[mf][0] = *(const i32x4*)(rdA + (BUF) + ((mb) + (mf)) * 2048 + swz[0]);\
    afr[mf][1] = *(const i32x4*)(rdA + (BUF) + ((mb) + (mf)) * 2048 + swz[1]);\
  } while (0)
#define RD_B(nf, BUF) do {                                                    \
    bfr[nf][0] = *(const i32x4*)(rdB + (BUF) + (nf) * 2048 + swz[0]);         \
    bfr[nf][1] = *(const i32x4*)(rdB + (BUF) + (nf) * 2048 + swz[1]);         \
  } while (0)

#define QUAD(MB, NB)                                                          \
    _Pragma("unroll") for (int mf = 0; mf < 4; ++mf)                          \
    _Pragma("unroll") for (int nf = 0; nf < 2; ++nf)                          \
    _Pragma("unroll") for (int kk = 0; kk < 2; ++kk)                          \
      acc[(MB) + mf][(NB) + nf] = __builtin_amdgcn_mfma_i32_16x16x64_i8(      \
          afr[mf][kk], bfr[(NB) + nf][kk], acc[(MB) + mf][(NB) + nf], 0, 0, 0)

#define PHASE_MID()                                         \
    __builtin_amdgcn_s_barrier();                           \
    asm volatile("s_waitcnt lgkmcnt(0)" ::: "memory");      \
    __builtin_amdgcn_sched_barrier(0);                      \
    __builtin_amdgcn_s_setprio(1)

#define PHASE_END()                                         \
    __builtin_amdgcn_s_setprio(0);                          \
    __builtin_amdgcn_s_barrier()

  // ---- prologue: A(0),B(0)->b0; B(1)->b1 (12 gloads); vmcnt(4): tile0 landed ----
  STAGE(gA,              lA,                 0);
  STAGE(gA + 128 * rowb, lA + 16384,         0);
  STAGE(gB,              lB,                 0);
  STAGE(gB + 128 * rowb, lB + 16384,         0);
  STAGE(gB,              lB + 32768,         128);   // B(1) h0
  STAGE(gB + 128 * rowb, lB + 32768 + 16384, 128);   // B(1) h1
  asm volatile("s_waitcnt vmcnt(4)" ::: "memory");   // A(0),B(0) landed; B(1) in flight
  __builtin_amdgcn_s_barrier();

  for (int T = 0; T < NT; T += 2) {
    const size_t kA1 = (size_t)(T + 1) * 128;
    const size_t kN2 = (size_t)(T + 2) * 128;
    const size_t kN3 = (size_t)(T + 3) * 128;
    const bool s2 = (T + 2 < NT), s3 = (T + 3 < NT);

    // ---------- ph1 : tile T (b0) ----------
    __builtin_amdgcn_sched_barrier(0);
#pragma unroll
    for (int mf = 0; mf < 4; ++mf) RD_A(mf, 0, 0);
    RD_B(0, 0); RD_B(1, 0);
    STAGE(gA, lA + 32768, kA1);                        // A(T+1)h0 -> b1
    asm volatile("s_waitcnt lgkmcnt(8)" ::: "memory"); // start draining the 12 reads
    PHASE_MID();
    QUAD(0, 0);
    PHASE_END();

    // ---------- ph2 ----------
    __builtin_amdgcn_sched_barrier(0);
    RD_B(2, 0); RD_B(3, 0);
    STAGE(gA + 128 * rowb, lA + 32768 + 16384, kA1);   // A(T+1)h1 -> b1
    PHASE_MID();
    QUAD(0, 2);
    PHASE_END();

    // ---------- ph3 ----------
    __builtin_amdgcn_sched_barrier(0);
#pragma unroll
    for (int mf = 0; mf < 4; ++mf) RD_A(mf, 4, 0);
    if (s2) STAGE(gB, lB, kN2);                        // B(T+2)h0 -> b0 (B-b0 read ph1-2)
    PHASE_MID();
    QUAD(4, 2);
    PHASE_END();

    // ---------- ph4 ----------
    __builtin_amdgcn_sched_barrier(0);
    if (s2) STAGE(gB + 128 * rowb, lB + 16384, kN2);   // B(T+2)h1 -> b0
    PHASE_MID();
    QUAD(4, 0);
    __builtin_amdgcn_s_setprio(0);
    if (s2) { asm volatile("s_waitcnt vmcnt(4)" ::: "memory"); }
    else    { asm volatile("s_waitcnt vmcnt(0)" ::: "memory"); }
    __builtin_amdgcn_s_barrier();

    // ---------- ph5 : tile T+1 (b1) ----------
    __builtin_amdgcn_sched_barrier(0);
#pragma unroll
    for (int mf = 0; mf < 4; ++mf) RD_A(mf, 0, 32768);
    RD_B(0, 32768); RD_B(1, 32768);
    if (s2) STAGE(gA, lA, kN2);                        // A(T+2)h0 -> b0 (A-b0 read ph1/ph3)
    asm volatile("s_waitcnt lgkmcnt(8)" ::: "memory");
    PHASE_MID();
    QUAD(0, 0);
    PHASE_END();

    // ---------- ph6 ----------
    __builtin_amdgcn_sched_barrier(0);
    RD_B(2, 32768); RD_B(3, 32768);
    if (s2) STAGE(gA + 128 * rowb, lA + 16384, kN2);   // A(T+2)h1 -> b0
    PHASE_MID();
    QUAD(0, 2);
    PHASE_END();

    // ---------- ph7 ----------
    __builtin_amdgcn_sched_barrier(0);
#pragma unroll
    for (int mf = 0; mf < 4; ++mf) RD_A(mf, 4, 32768);
    if (s3) STAGE(gB, lB + 32768, kN3);                // B(T+3)h0 -> b1 (B-b1 read ph5-6)
    PHASE_MID();
    QUAD(4, 2);
    PHASE_END();

    // ---------- ph8 ----------
    __builtin_amdgcn_sched_barrier(0);
    if (s3) STAGE(gB + 128 * rowb, lB + 32768 + 16384, kN3);  // B(T+3)h1 -> b1
    PHASE_MID();
    QUAD(4, 0);
    __builtin_amdgcn_s_setprio(0);
    if (s3) { asm volatile("s_waitcnt vmcnt(4)" ::: "memory"); }
    else    { asm volatile("s_waitcnt vmcnt(0)" ::: "memory"); }
    __builtin_amdgcn_s_barrier();
  }

  // ---- epilogue: C/D layout col = lane&15, row = (lane>>4)*4 + reg ----
  const int gr_base = trow * BM + wm * 128 + hi * 4;
  const int gc_base = tcol * BN + wn * 64 + lr;
  float sx[8][4];
#pragma unroll
  for (int mf = 0; mf < 8; ++mf)
#pragma unroll
    for (int j = 0; j < 4; ++j) sx[mf][j] = scale_x[gr_base + mf * 16 + j];
#pragma unroll
  for (int nf = 0; nf < 4; ++nf) {
    const int gc = gc_base + nf * 16;
    const float sw = scale_w[gc];
    const float bb = bias[gc];
#pragma unroll
    for (int mf = 0; mf < 8; ++mf) {
      const size_t rb = (size_t)(gr_base + mf * 16) * NOUT + gc;
#pragma unroll
      for (int j = 0; j < 4; ++j)
        __builtin_nontemporal_store((float)acc[mf][nf][j] * (sx[mf][j] * sw) + bb,
                                    &out[rb + (size_t)j * NOUT]);
    }
  }
#undef STAGE
#undef RD_A
#undef RD_B
#undef QUAD
#undef PHASE_MID
#undef PHASE_END
}

extern "C" void kernel_launch(void* const* d_in, const int* in_sizes, int n_in,
                              void* d_out, int out_size, void* d_ws, size_t ws_size,
                              hipStream_t stream) {
  const float* X  = (const float*)d_in[0];   // [8192, 4096] fp32
  const float* W  = (const float*)d_in[1];   // [11008, 4096] fp32
  const float* Bi = (const float*)d_in[2];   // [11008] fp32
  float* out = (float*)d_out;                // [8192, 11008] fp32

  const size_t xq_bytes = (size_t)TOKENS * KIN;      // 32 MiB
  const size_t wq_bytes = (size_t)NOUT * KIN;        // 43 MiB
  const size_t need = xq_bytes + wq_bytes + (size_t)(NOUT + TOKENS) * sizeof(float);
  if (ws_size < need) return;  // needs ~76 MB scratch

  char* ws = (char*)d_ws;
  signed char* Xq = (signed char*)ws;
  signed char* Wq = (signed char*)(ws + xq_bytes);
  float* scale_w = (float*)(ws + xq_bytes + wq_bytes);
  float* scale_x = scale_w + NOUT;

  quant_fused_k<<<NOUT + TOKENS, 256, 0, stream>>>(W, X, Wq, Xq, scale_w, scale_x);
  gemm_k<<<NWG, 512, 0, stream>>>(Xq, Wq, scale_x, scale_w, Bi, out);
}

// Round 13
// 418.898 us; speedup vs baseline: 1.2222x; 1.0263x over previous
//
#include <hip/hip_runtime.h>
#include <stdint.h>

#define TOKENS 8192
#define KIN    4096
#define NOUT   11008

// ---- 256x256 GEMM geometry (i8, BK=128 => 128 B/row) ----
#define BM 256
#define BN 256
#define BK 128
#define NT    (KIN / BK)      // 32 K-tiles
#define NTROW (TOKENS / BM)   // 32
#define NTCOL (NOUT / BN)     // 43
#define NWG   (NTROW * NTCOL) // 1376 = 8 XCDs x 172

using i32x4 = __attribute__((ext_vector_type(4))) int;

static __device__ __forceinline__ void gload_lds16(const void* g, void* l) {
  __builtin_amdgcn_global_load_lds((const __attribute__((address_space(1))) void*)g,
                                   (__attribute__((address_space(3))) void*)l,
                                   16, 0, 0);
}

static __device__ __forceinline__ int clamp_q(float f) {
  int q = (int)rintf(f);
  q = q > 127 ? 127 : q;
  q = q < -127 ? -127 : q;
  return q;
}

static __device__ __forceinline__ int pack4(int a, int b, int c, int d) {
  return (a & 0xff) | ((b & 0xff) << 8) | ((c & 0xff) << 16) | ((d & 0xff) << 24);
}

// ---- kernel 1: fused quantization (weight rows, then input rows; one launch) ----
__global__ __launch_bounds__(256) void quant_fused_k(const float* __restrict__ W,
                                                     const float* __restrict__ X,
                                                     signed char* __restrict__ Wq,
                                                     signed char* __restrict__ Xq,
                                                     float* __restrict__ scale_w,
                                                     float* __restrict__ scale_x) {
  const int bid = blockIdx.x;
  const int t   = threadIdx.x;
  if (bid < NOUT) {
    const int row = bid;
    const float4* wr = reinterpret_cast<const float4*>(W + (size_t)row * KIN);
    float4 v[4];
    double s = 0.0;
#pragma unroll
    for (int i = 0; i < 4; ++i) {
      v[i] = wr[t + i * 256];
      s += fabs((double)v[i].x) + fabs((double)v[i].y) +
           fabs((double)v[i].z) + fabs((double)v[i].w);
    }
#pragma unroll
    for (int off = 32; off > 0; off >>= 1) s += __shfl_down(s, off);
    __shared__ double redd[4];
    if ((t & 63) == 0) redd[t >> 6] = s;
    __syncthreads();
    const float sc = (float)((redd[0] + redd[1] + redd[2] + redd[3]) * (1.0 / KIN));
    if (t == 0) scale_w[row] = sc;
    int* qr = reinterpret_cast<int*>(Wq + (size_t)row * KIN);
#pragma unroll
    for (int i = 0; i < 4; ++i)
      qr[t + i * 256] = pack4(clamp_q(v[i].x / sc), clamp_q(v[i].y / sc),
                              clamp_q(v[i].z / sc), clamp_q(v[i].w / sc));
  } else {
    const int row = bid - NOUT;
    const float4* xr = reinterpret_cast<const float4*>(X + (size_t)row * KIN);
    float4 v[4];
    float amax = 0.f;
#pragma unroll
    for (int i = 0; i < 4; ++i) {
      v[i] = xr[t + i * 256];
      amax = fmaxf(amax, fmaxf(fmaxf(fabsf(v[i].x), fabsf(v[i].y)),
                               fmaxf(fabsf(v[i].z), fabsf(v[i].w))));
    }
#pragma unroll
    for (int off = 32; off > 0; off >>= 1) amax = fmaxf(amax, __shfl_down(amax, off));
    __shared__ float redf[4];
    if ((t & 63) == 0) redf[t >> 6] = amax;
    __syncthreads();
    amax = fmaxf(fmaxf(redf[0], redf[1]), fmaxf(redf[2], redf[3]));
    amax = fmaxf(amax, 1e-30f);
    const float inv = 127.0f / amax;
    if (t == 0) scale_x[row] = amax * (1.0f / 127.0f);
    int* qr = reinterpret_cast<int*>(Xq + (size_t)row * KIN);
#pragma unroll
    for (int i = 0; i < 4; ++i)
      qr[t + i * 256] = pack4(clamp_q(v[i].x * inv), clamp_q(v[i].y * inv),
                              clamp_q(v[i].z * inv), clamp_q(v[i].w * inv));
  }
}

// ---- kernel 2: 256x256x128 i8 GEMM, minimal-barrier schedule (R8, best timed) ----
// out[t,o] = s_x[t]*s_w[o]*(Xq[t,:].Wq[o,:])_i32 + bias[o].  Row-major [row][K] i8.
//
// R13 = R8 minus s_setprio (m190: setprio costs ~1.5% on coarse lockstep GEMM
// structures) + merged quant launch. Barrier invariants unchanged:
//   bar1: all waves consumed B-cur reads  -> stage B(t+2)->cur safe after it
//   bar2: all waves consumed A-cur reads  -> stage A(t+2)->cur safe after it
//   bar3 + vmcnt(8): tile t+1 staged data visible; tile t+2's 8 loads in flight
// "Consumed" = every ds_read feeds an MFMA before the next barrier (compiler's
// counted lgkm waits enforce completion before the consuming MFMA issues).
// sched_barrier(0) on BOTH sides of each s_barrier pins MFMAs/stages (rule #18).
__global__ __launch_bounds__(512, 2) void gemm_k(const signed char* __restrict__ Xq,
                                                 const signed char* __restrict__ Wq,
                                                 const float* __restrict__ scale_x,
                                                 const float* __restrict__ scale_w,
                                                 const float* __restrict__ bias,
                                                 float* __restrict__ out) {
  __shared__ alignas(16) char lds[131072];

  // ---- supertile swizzle (R6): 1376 = 8 XCDs x 172; 172 = 10 x (4x4) + 4x3 ----
  const int xcd = (int)blockIdx.x & 7;
  const int seq = (int)blockIdx.x >> 3;          // 0..171
  int trow, tcol;
  if (seq < 160) {
    const int chunk = seq >> 4;                  // 0..9
    const int rem   = seq & 15;
    trow = xcd * 4 + (rem >> 2);
    tcol = chunk * 4 + (rem & 3);
  } else {
    const int rem = seq - 160;                   // 0..11
    trow = xcd * 4 + rem / 3;
    tcol = 40 + rem % 3;
  }

  const int tid  = (int)threadIdx.x;
  const int lane = tid & 63;
  const int wave = tid >> 6;   // 0..7
  const int wm   = wave >> 2;  // 0..1 : M half (128 rows)
  const int wn   = wave & 3;   // 0..3 : N quarter (64 cols)

  // ---- staging lane addresses (inverse-swizzled global source, linear LDS dest) ----
  const int l8 = lane >> 3;                          // row within 8-row group
  const size_t rowb = (size_t)KIN;                   // 4096 B per row (i8)
  const int swzl = ((lane & 7) ^ l8) * 16;           // pre-swizzled slot within 128-B row chunk
  const char* gA = (const char*)Xq + (size_t)(trow * BM + wave * 16 + l8) * rowb + swzl;
  const char* gB = (const char*)Wq + (size_t)(tcol * BN + wave * 16 + l8) * rowb + swzl;
  char* lA = lds + wave * 2048;            // + buf*32768 + h*16384 (+1024 for 2nd gload)
  char* lB = lds + 65536 + wave * 2048;

#define STAGE(gp, lp, koff) do {                                             \
    gload_lds16((gp) + (koff), (lp));                                        \
    gload_lds16((gp) + (koff) + (size_t)(8 * 4096), (char*)(lp) + 1024);     \
  } while (0)

#define STAGE_B(CUR, KS) do {                                                \
    STAGE(gB,              lB + (CUR),         (KS));                        \
    STAGE(gB + 128 * rowb, lB + (CUR) + 16384, (KS));                        \
  } while (0)

#define STAGE_A(CUR, KS) do {                                                \
    STAGE(gA,              lA + (CUR),         (KS));                        \
    STAGE(gA + 128 * rowb, lA + (CUR) + 16384, (KS));                        \
  } while (0)

  // ---- ds_read bases (swizzled) ----
  const int lr = lane & 15;
  const int hi = lane >> 4;                          // 0..3 -> k-slot within 64-B k-slice
  const int swz0 = (hi * 16) ^ ((lr & 7) << 4);
  const int swz[2] = { swz0, swz0 ^ 64 };            // ks=0 / ks=1 (XOR: bit6 overlaps swizzle field)
  const char* rdA = lds + wm * 16384 + lr * 128;
  const char* rdB = lds + 65536 + (wn >> 1) * 16384 + ((wn & 1) * 64 + lr) * 128;

  i32x4 acc[8][4];
#pragma unroll
  for (int m = 0; m < 8; ++m)
#pragma unroll
    for (int n = 0; n < 4; ++n) acc[m][n] = (i32x4){0, 0, 0, 0};
  i32x4 afr[4][2], bfr[4][2];   // single set; afr reused m0-3 then m4-7

#define SB() __builtin_amdgcn_sched_barrier(0)
#define BAR() do { SB(); __builtin_amdgcn_s_barrier(); SB(); } while (0)

#define TILE(T, CUR) do {                                                     \
    const size_t kS = (size_t)((T) + 2) * 128;                                \
    /* region 1: A m0-3 + B n0-3 reads; MFMA m0-3 x n0-3 */                   \
    _Pragma("unroll") for (int mf = 0; mf < 4; ++mf) {                        \
      afr[mf][0] = *(const i32x4*)(rdA + (CUR) + mf * 2048 + swz[0]);         \
      afr[mf][1] = *(const i32x4*)(rdA + (CUR) + mf * 2048 + swz[1]);         \
    }                                                                         \
    _Pragma("unroll") for (int nf = 0; nf < 4; ++nf) {                        \
      bfr[nf][0] = *(const i32x4*)(rdB + (CUR) + nf * 2048 + swz[0]);         \
      bfr[nf][1] = *(const i32x4*)(rdB + (CUR) + nf * 2048 + swz[1]);         \
    }                                                                         \
    _Pragma("unroll") for (int mf = 0; mf < 4; ++mf)                          \
    _Pragma("unroll") for (int nf = 0; nf < 4; ++nf)                          \
    _Pragma("unroll") for (int kk = 0; kk < 2; ++kk)                          \
      acc[mf][nf] = __builtin_amdgcn_mfma_i32_16x16x64_i8(                    \
          afr[mf][kk], bfr[nf][kk], acc[mf][nf], 0, 0, 0);                    \
    BAR();  /* bar1: B-cur reads consumed by all waves */                     \
    if ((T) + 2 < NT) STAGE_B((CUR), kS);                                     \
    _Pragma("unroll") for (int mf = 0; mf < 4; ++mf) {                        \
      afr[mf][0] = *(const i32x4*)(rdA + (CUR) + (4 + mf) * 2048 + swz[0]);   \
      afr[mf][1] = *(const i32x4*)(rdA + (CUR) + (4 + mf) * 2048 + swz[1]);   \
    }                                                                         \
    _Pragma("unroll") for (int mf = 0; mf < 4; ++mf)                          \
    _Pragma("unroll") for (int nf = 2; nf < 4; ++nf)                          \
    _Pragma("unroll") for (int kk = 0; kk < 2; ++kk)                          \
      acc[4 + mf][nf] = __builtin_amdgcn_mfma_i32_16x16x64_i8(                \
          afr[mf][kk], bfr[nf][kk], acc[4 + mf][nf], 0, 0, 0);                \
    BAR();  /* bar2: A-cur reads consumed by all waves */                     \
    if ((T) + 2 < NT) STAGE_A((CUR), kS);                                     \
    _Pragma("unroll") for (int mf = 0; mf < 4; ++mf)                          \
    _Pragma("unroll") for (int nf = 0; nf < 2; ++nf)                          \
    _Pragma("unroll") for (int kk = 0; kk < 2; ++kk)                          \
      acc[4 + mf][nf] = __builtin_amdgcn_mfma_i32_16x16x64_i8(                \
          afr[mf][kk], bfr[nf][kk], acc[4 + mf][nf], 0, 0, 0);                \
    if ((T) < NT - 2) { asm volatile("s_waitcnt vmcnt(8)" ::: "memory"); }    \
    else              { asm volatile("s_waitcnt vmcnt(0)" ::: "memory"); }    \
    BAR();  /* bar3: tile T+1 staged data visible to all waves */             \
  } while (0)

  // ---- prologue: stage tiles 0 and 1 fully (16 loads); wait tile0 (vmcnt(8)) ----
  STAGE_A(0,     0);
  STAGE_B(0,     0);
  STAGE_A(32768, 128);
  STAGE_B(32768, 128);
  asm volatile("s_waitcnt vmcnt(8)" ::: "memory");  // tile0 landed; tile1 in flight
  BAR();

  for (int tt = 0; tt < NT; tt += 2) {
    TILE(tt,     0);
    TILE(tt + 1, 32768);
  }

  // ---- epilogue: C/D layout col = lane&15, row = (lane>>4)*4 + reg (dtype-independent) ----
  const int gr_base = trow * BM + wm * 128 + hi * 4;
  const int gc_base = tcol * BN + wn * 64 + lr;
  float sx[8][4];
#pragma unroll
  for (int mf = 0; mf < 8; ++mf)
#pragma unroll
    for (int j = 0; j < 4; ++j) sx[mf][j] = scale_x[gr_base + mf * 16 + j];
#pragma unroll
  for (int nf = 0; nf < 4; ++nf) {
    const int gc = gc_base + nf * 16;
    const float sw = scale_w[gc];
    const float bb = bias[gc];
#pragma unroll
    for (int mf = 0; mf < 8; ++mf) {
      const size_t rb = (size_t)(gr_base + mf * 16) * NOUT + gc;
#pragma unroll
      for (int j = 0; j < 4; ++j)
        __builtin_nontemporal_store((float)acc[mf][nf][j] * (sx[mf][j] * sw) + bb,
                                    &out[rb + (size_t)j * NOUT]);
    }
  }
#undef STAGE
#undef STAGE_A
#undef STAGE_B
#undef TILE
#undef SB
#undef BAR
}

extern "C" void kernel_launch(void* const* d_in, const int* in_sizes, int n_in,
                              void* d_out, int out_size, void* d_ws, size_t ws_size,
                              hipStream_t stream) {
  const float* X  = (const float*)d_in[0];   // [8192, 4096] fp32
  const float* W  = (const float*)d_in[1];   // [11008, 4096] fp32
  const float* Bi = (const float*)d_in[2];   // [11008] fp32
  float* out = (float*)d_out;                // [8192, 11008] fp32

  const size_t xq_bytes = (size_t)TOKENS * KIN;      // 32 MiB
  const size_t wq_bytes = (size_t)NOUT * KIN;        // 43 MiB
  const size_t need = xq_bytes + wq_bytes + (size_t)(NOUT + TOKENS) * sizeof(float);
  if (ws_size < need) return;  // needs ~76 MB scratch

  char* ws = (char*)d_ws;
  signed char* Xq = (signed char*)ws;
  signed char* Wq = (signed char*)(ws + xq_bytes);
  float* scale_w = (float*)(ws + xq_bytes + wq_bytes);
  float* scale_x = scale_w + NOUT;

  quant_fused_k<<<NOUT + TOKENS, 256, 0, stream>>>(W, X, Wq, Xq, scale_w, scale_x);
  gemm_k<<<NWG, 512, 0, stream>>>(Xq, Wq, scale_x, scale_w, Bi, out);
}